// Round 1
// baseline (4499.969 us; speedup 1.0000x reference)
//
#include <hip/hip_runtime.h>
#include <math.h>

// Problem constants
#define BB 16
#define TT 2048
#define DD 512
#define WW 12
#define TQ 512              // TT/4 selected queries per batch
#define NROWS (BB * TQ)     // 8192 GRU batch rows

// GEMM tiling
#define BM 64
#define BN 64
#define KB 16

__device__ __forceinline__ float sigmoidf_(float v) { return 1.0f / (1.0f + expf(-v)); }

// -------- Kernel 1: band top-k selection (fp64 scores, exact ranking) -------
// One wave per (b, qi). Candidates j in [t-11, t+11] clipped; >= 12 always.
__global__ __launch_bounds__(64) void select_topk_kernel(
    const float* __restrict__ x, int* __restrict__ ids)
{
    const int n = blockIdx.x;          // 0..NROWS-1
    const int b = n / TQ;
    const int qi = n - b * TQ;
    const int lane = threadIdx.x;      // 0..63

    // numpy linspace(0, T-1, TQ): y[i] = i * ((T-1)/(TQ-1)) in double, truncate;
    // endpoint forced exact.
    int t;
    if (qi == TQ - 1) t = TT - 1;
    else t = (int)((double)qi * ((double)(TT - 1) / (double)(TQ - 1)));

    int j0 = t - (WW - 1); if (j0 < 0) j0 = 0;
    int j1 = t + (WW - 1); if (j1 > TT - 1) j1 = TT - 1;
    const int ncand = j1 - j0 + 1;     // <= 23

    const float* xq = x + ((size_t)b * TT + t) * DD;
    double q[8];
#pragma unroll
    for (int i = 0; i < 8; ++i) q[i] = (double)xq[lane * 8 + i];

    __shared__ double sc[2 * WW - 1];
    for (int c = 0; c < ncand; ++c) {
        const float* xk = x + ((size_t)b * TT + (j0 + c)) * DD;
        double s = 0.0;
#pragma unroll
        for (int i = 0; i < 8; ++i) s += q[i] * (double)xk[lane * 8 + i];
#pragma unroll
        for (int off = 32; off > 0; off >>= 1) s += __shfl_xor(s, off);
        if (lane == 0) sc[c] = s;
    }
    __syncthreads();

    if (lane == 0) {
        // top-12 by score, ties -> lower index (matches lax.top_k)
        int sel[WW];
        unsigned used = 0;
        for (int k = 0; k < WW; ++k) {
            int best = -1; double bs = 0.0;
            for (int c = 0; c < ncand; ++c) {
                if (used & (1u << c)) continue;
                if (best < 0 || sc[c] > bs) { bs = sc[c]; best = c; }
            }
            used |= (1u << best);
            sel[k] = j0 + best;
        }
        // sort ascending
        for (int i = 1; i < WW; ++i) {
            int v = sel[i]; int j = i - 1;
            while (j >= 0 && sel[j] > v) { sel[j + 1] = sel[j]; --j; }
            sel[j + 1] = v;
        }
#pragma unroll
        for (int k = 0; k < WW; ++k) ids[(size_t)n * WW + k] = sel[k];
    }
}

// -------- Kernel 2: one fused GRU step ------------------------------------
// h_new[n][c] for a BM x BN tile; gathers xt rows via ids; 3 gates fused.
// acc_r, acc_z combine the xt- and h- products; i_n / h_n kept separate.
__global__ __launch_bounds__(256) void gru_step_kernel(
    const float* __restrict__ x,
    const int* __restrict__ ids,
    const float* __restrict__ w_ih,
    const float* __restrict__ w_hh,
    const float* __restrict__ b_ih,
    const float* __restrict__ b_hh,
    const float* __restrict__ hin,
    float* __restrict__ hout,
    int step)
{
    __shared__ __align__(16) float sXT[KB][BM];       // [k][row] gathered x
    __shared__ __align__(16) float sHT[KB][BM];       // [k][row] h
    __shared__ __align__(16) float sWi[3][KB][BN];    // [gate][k][col]
    __shared__ __align__(16) float sWh[3][KB][BN];
    __shared__ int sXrow[BM];                         // gathered source row (b*T+id)

    const int tid = threadIdx.x;
    const int c0 = blockIdx.x * BN;
    const int n0 = blockIdx.y * BM;

    if (tid < BM) {
        int n = n0 + tid;
        int b = n / TQ;
        int id = ids[(size_t)n * WW + step];
        sXrow[tid] = b * TT + id;
    }
    __syncthreads();

    float accR[4][4] = {{0.f}}, accZ[4][4] = {{0.f}};
    float accIN[4][4] = {{0.f}}, accHN[4][4] = {{0.f}};

    const int lr = tid >> 2;            // 0..63 : row (A) / col (B) for loads
    const int lk = (tid & 3) << 2;      // 0,4,8,12 : k offset for loads
    const int tr = (tid >> 4) << 2;     // thread row base (compute)
    const int tc = (tid & 15) << 2;     // thread col base (compute)

    for (int k0 = 0; k0 < DD; k0 += KB) {
        // issue global loads into registers first (overlap with barrier)
        float4 vx = *reinterpret_cast<const float4*>(x + (size_t)sXrow[lr] * DD + (k0 + lk));
        float4 vh = *reinterpret_cast<const float4*>(hin + (size_t)(n0 + lr) * DD + (k0 + lk));
        float4 vi0 = *reinterpret_cast<const float4*>(w_ih + ((size_t)(0 * DD + c0 + lr)) * DD + (k0 + lk));
        float4 vi1 = *reinterpret_cast<const float4*>(w_ih + ((size_t)(1 * DD + c0 + lr)) * DD + (k0 + lk));
        float4 vi2 = *reinterpret_cast<const float4*>(w_ih + ((size_t)(2 * DD + c0 + lr)) * DD + (k0 + lk));
        float4 vh0 = *reinterpret_cast<const float4*>(w_hh + ((size_t)(0 * DD + c0 + lr)) * DD + (k0 + lk));
        float4 vh1 = *reinterpret_cast<const float4*>(w_hh + ((size_t)(1 * DD + c0 + lr)) * DD + (k0 + lk));
        float4 vh2 = *reinterpret_cast<const float4*>(w_hh + ((size_t)(2 * DD + c0 + lr)) * DD + (k0 + lk));

        __syncthreads();   // previous iteration's compute done reading LDS

        sXT[lk + 0][lr] = vx.x; sXT[lk + 1][lr] = vx.y; sXT[lk + 2][lr] = vx.z; sXT[lk + 3][lr] = vx.w;
        sHT[lk + 0][lr] = vh.x; sHT[lk + 1][lr] = vh.y; sHT[lk + 2][lr] = vh.z; sHT[lk + 3][lr] = vh.w;
        sWi[0][lk + 0][lr] = vi0.x; sWi[0][lk + 1][lr] = vi0.y; sWi[0][lk + 2][lr] = vi0.z; sWi[0][lk + 3][lr] = vi0.w;
        sWi[1][lk + 0][lr] = vi1.x; sWi[1][lk + 1][lr] = vi1.y; sWi[1][lk + 2][lr] = vi1.z; sWi[1][lk + 3][lr] = vi1.w;
        sWi[2][lk + 0][lr] = vi2.x; sWi[2][lk + 1][lr] = vi2.y; sWi[2][lk + 2][lr] = vi2.z; sWi[2][lk + 3][lr] = vi2.w;
        sWh[0][lk + 0][lr] = vh0.x; sWh[0][lk + 1][lr] = vh0.y; sWh[0][lk + 2][lr] = vh0.z; sWh[0][lk + 3][lr] = vh0.w;
        sWh[1][lk + 0][lr] = vh1.x; sWh[1][lk + 1][lr] = vh1.y; sWh[1][lk + 2][lr] = vh1.z; sWh[1][lk + 3][lr] = vh1.w;
        sWh[2][lk + 0][lr] = vh2.x; sWh[2][lk + 1][lr] = vh2.y; sWh[2][lk + 2][lr] = vh2.z; sWh[2][lk + 3][lr] = vh2.w;

        __syncthreads();   // tiles visible

#pragma unroll
        for (int kk = 0; kk < KB; ++kk) {
            float ax[4], ah[4], wr0[4], wz0[4], wn0[4], wr1[4], wz1[4], wn1[4];
            *(float4*)ax  = *(const float4*)&sXT[kk][tr];
            *(float4*)ah  = *(const float4*)&sHT[kk][tr];
            *(float4*)wr0 = *(const float4*)&sWi[0][kk][tc];
            *(float4*)wz0 = *(const float4*)&sWi[1][kk][tc];
            *(float4*)wn0 = *(const float4*)&sWi[2][kk][tc];
            *(float4*)wr1 = *(const float4*)&sWh[0][kk][tc];
            *(float4*)wz1 = *(const float4*)&sWh[1][kk][tc];
            *(float4*)wn1 = *(const float4*)&sWh[2][kk][tc];
#pragma unroll
            for (int i = 0; i < 4; ++i) {
#pragma unroll
                for (int j = 0; j < 4; ++j) {
                    accR[i][j]  = fmaf(ax[i], wr0[j], fmaf(ah[i], wr1[j], accR[i][j]));
                    accZ[i][j]  = fmaf(ax[i], wz0[j], fmaf(ah[i], wz1[j], accZ[i][j]));
                    accIN[i][j] = fmaf(ax[i], wn0[j], accIN[i][j]);
                    accHN[i][j] = fmaf(ah[i], wn1[j], accHN[i][j]);
                }
            }
        }
    }

    // epilogue: gates + state update
    float bir[4], biz[4], bin_[4], bhr[4], bhz[4], bhn[4];
#pragma unroll
    for (int j = 0; j < 4; ++j) {
        int c = c0 + tc + j;
        bir[j]  = b_ih[c];          bhr[j] = b_hh[c];
        biz[j]  = b_ih[DD + c];     bhz[j] = b_hh[DD + c];
        bin_[j] = b_ih[2 * DD + c]; bhn[j] = b_hh[2 * DD + c];
    }
#pragma unroll
    for (int i = 0; i < 4; ++i) {
        int row = n0 + tr + i;
        const float* hprow = hin + (size_t)row * DD + (c0 + tc);
        float* horow = hout + (size_t)row * DD + (c0 + tc);
        float4 hp = *(const float4*)hprow;
        float hparr[4] = {hp.x, hp.y, hp.z, hp.w};
        float res[4];
#pragma unroll
        for (int j = 0; j < 4; ++j) {
            float rg = sigmoidf_(accR[i][j] + bir[j] + bhr[j]);
            float zg = sigmoidf_(accZ[i][j] + biz[j] + bhz[j]);
            float ng = tanhf(accIN[i][j] + bin_[j] + rg * (accHN[i][j] + bhn[j]));
            res[j] = (1.0f - zg) * ng + zg * hparr[j];
        }
        *(float4*)horow = make_float4(res[0], res[1], res[2], res[3]);
    }
}

// ---------------------------------------------------------------------------
extern "C" void kernel_launch(void* const* d_in, const int* in_sizes, int n_in,
                              void* d_out, int out_size, void* d_ws, size_t ws_size,
                              hipStream_t stream)
{
    const float* x    = (const float*)d_in[0];
    const float* w_ih = (const float*)d_in[1];
    const float* w_hh = (const float*)d_in[2];
    const float* b_ih = (const float*)d_in[3];
    const float* b_hh = (const float*)d_in[4];

    // workspace layout: [ids: NROWS*WW int32][pad to 1MB][h pong: NROWS*DD f32]
    int*   ids = (int*)d_ws;
    float* hA  = (float*)d_out;                        // ping (holds h0=0 and final h)
    float* hB  = (float*)((char*)d_ws + (1u << 20));   // pong

    select_topk_kernel<<<dim3(NROWS), dim3(64), 0, stream>>>(x, ids);
    hipMemsetAsync(d_out, 0, (size_t)NROWS * DD * sizeof(float), stream);

    for (int s = 0; s < WW; ++s) {
        const float* hin = (s & 1) ? hB : hA;
        float* hout      = (s & 1) ? hA : hB;
        gru_step_kernel<<<dim3(DD / BN, NROWS / BM), dim3(256), 0, stream>>>(
            x, ids, w_ih, w_hh, b_ih, b_hh, hin, hout, s);
    }
    // 12 steps (even): final write lands in hA == d_out
}

// Round 2
// 897.673 us; speedup vs baseline: 5.0129x; 5.0129x over previous
//
#include <hip/hip_runtime.h>
#include <math.h>

// Problem constants
#define BB 16
#define TT 2048
#define DD 512
#define WW 12
#define TQ 512
#define NROWS (BB * TQ)

typedef _Float16 f16;
typedef __attribute__((ext_vector_type(8))) _Float16 f16x8;
typedef __attribute__((ext_vector_type(4))) _Float16 f16x4;
typedef __attribute__((ext_vector_type(4))) float f32x4;

#define MFMA16(a, b, c) __builtin_amdgcn_mfma_f32_16x16x32_f16((a), (b), (c), 0, 0, 0)

// ws layout (proven budget >= 17.8 MB; we use 12 MB)
#define WS_IDS  0u
#define WS_W16  (512u * 1024u)              // 3072 rows x 512 f16 = 3 MB ([w_ih ; w_hh])
#define WS_H16  (4u * 1024u * 1024u)        // 8192 x 512 f16 = 8 MB (ping)

__device__ __forceinline__ float fsigm(float v) { return 1.0f / (1.0f + __expf(-v)); }
__device__ __forceinline__ float ftanh(float v) {
    float a = fabsf(v);
    float t = __expf(-2.0f * a);
    float r = (1.0f - t) / (1.0f + t);
    return copysignf(r, v);
}

__device__ __forceinline__ f16x8 cvt8(float4 a, float4 b) {
    f16x8 r;
    r[0] = (_Float16)a.x; r[1] = (_Float16)a.y; r[2] = (_Float16)a.z; r[3] = (_Float16)a.w;
    r[4] = (_Float16)b.x; r[5] = (_Float16)b.y; r[6] = (_Float16)b.z; r[7] = (_Float16)b.w;
    return r;
}

// -------- Kernel 1: band top-k selection (fp64 scores, exact ranking) -------
__global__ __launch_bounds__(64) void select_topk_kernel(
    const float* __restrict__ x, int* __restrict__ ids)
{
    const int n = blockIdx.x;
    const int b = n / TQ;
    const int qi = n - b * TQ;
    const int lane = threadIdx.x;

    int t;
    if (qi == TQ - 1) t = TT - 1;
    else t = (int)((double)qi * ((double)(TT - 1) / (double)(TQ - 1)));

    int j0 = t - (WW - 1); if (j0 < 0) j0 = 0;
    int j1 = t + (WW - 1); if (j1 > TT - 1) j1 = TT - 1;
    const int ncand = j1 - j0 + 1;

    const float* xq = x + ((size_t)b * TT + t) * DD;
    double q[8];
#pragma unroll
    for (int i = 0; i < 8; ++i) q[i] = (double)xq[lane * 8 + i];

    __shared__ double sc[2 * WW - 1];
    for (int c = 0; c < ncand; ++c) {
        const float* xk = x + ((size_t)b * TT + (j0 + c)) * DD;
        double s = 0.0;
#pragma unroll
        for (int i = 0; i < 8; ++i) s += q[i] * (double)xk[lane * 8 + i];
#pragma unroll
        for (int off = 32; off > 0; off >>= 1) s += __shfl_xor(s, off);
        if (lane == 0) sc[c] = s;
    }
    __syncthreads();

    if (lane == 0) {
        int sel[WW];
        unsigned used = 0;
        for (int k = 0; k < WW; ++k) {
            int best = -1; double bs = 0.0;
            for (int c = 0; c < ncand; ++c) {
                if (used & (1u << c)) continue;
                if (best < 0 || sc[c] > bs) { bs = sc[c]; best = c; }
            }
            used |= (1u << best);
            sel[k] = j0 + best;
        }
        for (int i = 1; i < WW; ++i) {
            int v = sel[i]; int j = i - 1;
            while (j >= 0 && sel[j] > v) { sel[j + 1] = sel[j]; --j; }
            sel[j + 1] = v;
        }
#pragma unroll
        for (int k = 0; k < WW; ++k) ids[(size_t)n * WW + k] = sel[k];
    }
}

// -------- Kernel 2: f32 -> f16 weight conversion (combined [w_ih; w_hh]) ----
__global__ __launch_bounds__(256) void convert_w_kernel(
    const float* __restrict__ wi, const float* __restrict__ wh, f16* __restrict__ w16)
{
    const int PER = 3 * DD * DD / 4;               // 196608 float4-groups per matrix
    int i = blockIdx.x * 256 + threadIdx.x;        // 0 .. 2*PER-1
    float4 v;
    if (i < PER) v = ((const float4*)wi)[i];
    else         v = ((const float4*)wh)[i - PER];
    f16x4 o;
    o[0] = (_Float16)v.x; o[1] = (_Float16)v.y; o[2] = (_Float16)v.z; o[3] = (_Float16)v.w;
    *(f16x4*)(w16 + (size_t)i * 4) = o;
}

// -------- Kernel 3: one fused GRU step, f16 MFMA --------------------------
// Block: 256 thr / 4 waves; tile 128 rows x 64 cols; wave 64x32 (4 mf x 2 nf).
// Weights staged in LDS (48 KB, XOR-swizzled); x gathered f32->f16 on the fly;
// h read from f16 ping-pong. 4 accumulator groups: R, Z, IN, HN.
__global__ __launch_bounds__(256, 2) void gru_step_kernel(
    const float* __restrict__ x,
    const int* __restrict__ ids,
    const f16* __restrict__ w16,        // [3072][512]: rows 0-1535 w_ih, 1536-3071 w_hh
    const float* __restrict__ b_ih,
    const float* __restrict__ b_hh,
    const f16* __restrict__ h16r,
    f16* __restrict__ h16w,             // null on last step
    float* __restrict__ f32w,           // null except last step
    int step)
{
    __shared__ __align__(16) char sW[48 * 1024];
    __shared__ int sXrow[128];

    const int tid = threadIdx.x;
    const int lane = tid & 63, wid = tid >> 6;
    const int wm = wid >> 1, wn = wid & 1;
    const int l15 = lane & 15, lhi = lane >> 4;
    const int bid = blockIdx.x;
    const int rb = bid & 63, cb = bid >> 6;     // same rb -> same XCD (bid%8 preserved)
    const int row0 = rb * 128, c0 = cb * 64;

    if (tid < 128) {
        int n = row0 + tid;
        int b = n >> 9;                          // TQ = 512
        sXrow[tid] = b * TT + ids[(size_t)n * WW + step];
    }

    // staging precompute: 12 chunks of 1KB per wave; chunk = (gate-tile g, col-group)
    // LDS layout: [6][64 cols][64 k] f16, row = 128 B = 8 slots of 16 B.
    // slot s of col holds global k-chunk (s ^ (col&7))  -> swizzled reads are conflict-free.
    unsigned stOff[12];
    {
        const int slot = lane & 7, lc = lane >> 3;
#pragma unroll
        for (int i = 0; i < 12; ++i) {
            int ch = wid * 12 + i;
            int g = ch >> 3, cg = ch & 7;
            int col = cg * 8 + lc;
            int srck = ((slot ^ (col & 7)) << 3);            // element offset in 64-k tile
            unsigned grow = (unsigned)(g * 512 + c0 + col);  // row in combined w16
            stOff[i] = grow * 1024u + (unsigned)(srck * 2);  // bytes (row stride 1024 B)
        }
    }
    char* ldsDst = sW + wid * 12 * 1024;

    // B-fragment read bases (swizzled)
    const int col0 = wn * 32 + l15;
    const unsigned swz = (unsigned)((lhi ^ (col0 & 7)) << 4);
    const char* bb0 = sW + col0 * 128 + swz;
    const char* bb1 = sW + col0 * 128 + (swz ^ 64u);

    f32x4 accR[4][2], accZ[4][2], accIN[4][2], accHN[4][2];
#pragma unroll
    for (int mf = 0; mf < 4; ++mf)
#pragma unroll
        for (int nf = 0; nf < 2; ++nf) {
            f32x4 z = {0.f, 0.f, 0.f, 0.f};
            accR[mf][nf] = z; accZ[mf][nf] = z; accIN[mf][nf] = z; accHN[mf][nf] = z;
        }

    __syncthreads();                              // sXrow visible

    // stage k-step 0
#pragma unroll
    for (int i = 0; i < 12; ++i) {
        const char* src = (const char*)w16 + stOff[i];
        __builtin_amdgcn_global_load_lds(
            (const __attribute__((address_space(1))) unsigned*)src,
            (__attribute__((address_space(3))) unsigned*)(ldsDst + i * 1024), 16, 0, 0);
    }

    const float* xp[4]; const char* hp[4]; int rowA[4];
#pragma unroll
    for (int mf = 0; mf < 4; ++mf) {
        int rl = wm * 64 + mf * 16 + l15;
        rowA[mf] = row0 + rl;
        int srow = sXrow[rl];
        xp[mf] = x + (size_t)srow * DD + lhi * 8;
        hp[mf] = (const char*)(h16r + (size_t)(row0 + rl) * DD + lhi * 8);
    }

    for (int ks = 0; ks < 8; ++ks) {
        const int k0 = ks * 64;
        asm volatile("s_waitcnt vmcnt(0)" ::: "memory");
        __syncthreads();                          // staged tile visible

        // A loads ksub0
        float4 xa[4], xb[4]; uint4 ha[4];
#pragma unroll
        for (int mf = 0; mf < 4; ++mf) {
            xa[mf] = *(const float4*)(xp[mf] + k0);
            xb[mf] = *(const float4*)(xp[mf] + k0 + 4);
            ha[mf] = *(const uint4*)(hp[mf] + k0 * 2);
        }
        f16x8 ax[4], ah[4];
#pragma unroll
        for (int mf = 0; mf < 4; ++mf) { ax[mf] = cvt8(xa[mf], xb[mf]); ah[mf] = *(const f16x8*)&ha[mf]; }

        // issue A loads ksub1 (hide under ksub0 MFMAs)
        float4 xc[4], xd[4]; uint4 hb[4];
#pragma unroll
        for (int mf = 0; mf < 4; ++mf) {
            xc[mf] = *(const float4*)(xp[mf] + k0 + 32);
            xd[mf] = *(const float4*)(xp[mf] + k0 + 36);
            hb[mf] = *(const uint4*)(hp[mf] + k0 * 2 + 64);
        }

        // ksub0 MFMAs
#pragma unroll
        for (int nf = 0; nf < 2; ++nf) {
            const char* bb = bb0 + nf * 2048;
            f16x8 b0 = *(const f16x8*)(bb + 0 * 8192);
            f16x8 b1 = *(const f16x8*)(bb + 1 * 8192);
            f16x8 b2 = *(const f16x8*)(bb + 2 * 8192);
            f16x8 b3 = *(const f16x8*)(bb + 3 * 8192);
            f16x8 b4 = *(const f16x8*)(bb + 4 * 8192);
            f16x8 b5 = *(const f16x8*)(bb + 5 * 8192);
#pragma unroll
            for (int mf = 0; mf < 4; ++mf) {
                accR[mf][nf]  = MFMA16(ax[mf], b0, accR[mf][nf]);
                accR[mf][nf]  = MFMA16(ah[mf], b3, accR[mf][nf]);
                accZ[mf][nf]  = MFMA16(ax[mf], b1, accZ[mf][nf]);
                accZ[mf][nf]  = MFMA16(ah[mf], b4, accZ[mf][nf]);
                accIN[mf][nf] = MFMA16(ax[mf], b2, accIN[mf][nf]);
                accHN[mf][nf] = MFMA16(ah[mf], b5, accHN[mf][nf]);
            }
        }

        // ksub1
#pragma unroll
        for (int mf = 0; mf < 4; ++mf) { ax[mf] = cvt8(xc[mf], xd[mf]); ah[mf] = *(const f16x8*)&hb[mf]; }
#pragma unroll
        for (int nf = 0; nf < 2; ++nf) {
            const char* bb = bb1 + nf * 2048;
            f16x8 b0 = *(const f16x8*)(bb + 0 * 8192);
            f16x8 b1 = *(const f16x8*)(bb + 1 * 8192);
            f16x8 b2 = *(const f16x8*)(bb + 2 * 8192);
            f16x8 b3 = *(const f16x8*)(bb + 3 * 8192);
            f16x8 b4 = *(const f16x8*)(bb + 4 * 8192);
            f16x8 b5 = *(const f16x8*)(bb + 5 * 8192);
#pragma unroll
            for (int mf = 0; mf < 4; ++mf) {
                accR[mf][nf]  = MFMA16(ax[mf], b0, accR[mf][nf]);
                accR[mf][nf]  = MFMA16(ah[mf], b3, accR[mf][nf]);
                accZ[mf][nf]  = MFMA16(ax[mf], b1, accZ[mf][nf]);
                accZ[mf][nf]  = MFMA16(ah[mf], b4, accZ[mf][nf]);
                accIN[mf][nf] = MFMA16(ax[mf], b2, accIN[mf][nf]);
                accHN[mf][nf] = MFMA16(ah[mf], b5, accHN[mf][nf]);
            }
        }

        if (ks < 7) {
            __syncthreads();                      // all reads of sW done
            const int kn = k0 + 64;
#pragma unroll
            for (int i = 0; i < 12; ++i) {
                const char* src = (const char*)w16 + stOff[i] + (unsigned)(kn * 2);
                __builtin_amdgcn_global_load_lds(
                    (const __attribute__((address_space(1))) unsigned*)src,
                    (__attribute__((address_space(3))) unsigned*)(ldsDst + i * 1024), 16, 0, 0);
            }
        }
    }

    // epilogue: gates + state update
#pragma unroll
    for (int nf = 0; nf < 2; ++nf) {
        int col = c0 + wn * 32 + nf * 16 + l15;
        float bir = b_ih[col],          bhr = b_hh[col];
        float biz = b_ih[DD + col],     bhz = b_hh[DD + col];
        float bin = b_ih[2 * DD + col], bhn = b_hh[2 * DD + col];
#pragma unroll
        for (int mf = 0; mf < 4; ++mf) {
#pragma unroll
            for (int r = 0; r < 4; ++r) {
                int row = row0 + wm * 64 + mf * 16 + lhi * 4 + r;
                size_t off = (size_t)row * DD + col;
                float hold = (float)h16r[off];
                float R = fsigm(accR[mf][nf][r] + bir + bhr);
                float Z = fsigm(accZ[mf][nf][r] + biz + bhz);
                float Nn = ftanh(accIN[mf][nf][r] + bin + R * (accHN[mf][nf][r] + bhn));
                float res = (1.0f - Z) * Nn + Z * hold;
                if (h16w) h16w[off] = (f16)res;
                if (f32w) f32w[off] = res;
            }
        }
    }
}

// ---------------------------------------------------------------------------
extern "C" void kernel_launch(void* const* d_in, const int* in_sizes, int n_in,
                              void* d_out, int out_size, void* d_ws, size_t ws_size,
                              hipStream_t stream)
{
    const float* x    = (const float*)d_in[0];
    const float* w_ih = (const float*)d_in[1];
    const float* w_hh = (const float*)d_in[2];
    const float* b_ih = (const float*)d_in[3];
    const float* b_hh = (const float*)d_in[4];

    char* ws = (char*)d_ws;
    int*  ids   = (int*)(ws + WS_IDS);
    f16*  w16   = (f16*)(ws + WS_W16);
    f16*  h16ws = (f16*)(ws + WS_H16);
    f16*  h16do = (f16*)d_out;                     // ping buffer aliasing d_out

    select_topk_kernel<<<dim3(NROWS), dim3(64), 0, stream>>>(x, ids);
    convert_w_kernel<<<dim3(1536), dim3(256), 0, stream>>>(w_ih, w_hh, w16);
    hipMemsetAsync(d_out, 0, (size_t)NROWS * DD * sizeof(f16), stream);   // h0 = 0

    for (int s = 0; s < WW; ++s) {
        const f16* hr = (s & 1) ? h16ws : (const f16*)h16do;
        f16* hw      = (s == WW - 1) ? nullptr : ((s & 1) ? h16do : h16ws);
        float* fo    = (s == WW - 1) ? (float*)d_out : nullptr;
        gru_step_kernel<<<dim3(512), dim3(256), 0, stream>>>(
            x, ids, w16, b_ih, b_hh, hr, hw, fo, s);
    }
}

// Round 3
// 881.040 us; speedup vs baseline: 5.1076x; 1.0189x over previous
//
#include <hip/hip_runtime.h>
#include <math.h>

// Problem constants
#define BB 16
#define TT 2048
#define DD 512
#define WW 12
#define TQ 512
#define NROWS (BB * TQ)

typedef _Float16 f16;
typedef __attribute__((ext_vector_type(8))) _Float16 f16x8;
typedef __attribute__((ext_vector_type(4))) _Float16 f16x4;
typedef __attribute__((ext_vector_type(4))) float f32x4;

#define MFMA16(a, b, c) __builtin_amdgcn_mfma_f32_16x16x32_f16((a), (b), (c), 0, 0, 0)

// ws layout
#define WS_IDS  0u
#define WS_W16  (512u * 1024u)              // 3072 x 512 f16 = 3 MB ([w_ih ; w_hh])
#define WS_H16  (4u * 1024u * 1024u)        // 8192 x 512 f16 = 8 MB (ping)

__device__ __forceinline__ float fsigm(float v) { return 1.0f / (1.0f + __expf(-v)); }
__device__ __forceinline__ float ftanh(float v) {
    float a = fabsf(v);
    float t = __expf(-2.0f * a);
    float r = (1.0f - t) / (1.0f + t);
    return copysignf(r, v);
}

__device__ __forceinline__ f16x8 cvt8(float4 a, float4 b) {
    f16x8 r;
    r[0] = (_Float16)a.x; r[1] = (_Float16)a.y; r[2] = (_Float16)a.z; r[3] = (_Float16)a.w;
    r[4] = (_Float16)b.x; r[5] = (_Float16)b.y; r[6] = (_Float16)b.z; r[7] = (_Float16)b.w;
    return r;
}

// -------- Kernel 1: band top-k selection, parallel candidates ---------------
// 256 thr = 4 waves = 4 queries. Per wave: lane = (c, i); c in 0..15 candidate
// stream, i in 0..3 k-slice. 2 rounds cover <=23 candidates. fp64 accumulate.
__global__ __launch_bounds__(256) void select_topk_kernel(
    const float* __restrict__ x, int* __restrict__ ids)
{
    const int tid = threadIdx.x, wid = tid >> 6, lane = tid & 63;
    const int bid = blockIdx.x;                    // 0..2047
    const int swz = (bid & 7) * 256 + (bid >> 3);  // XCD-chunked: 256 blocks/XCD contiguous
    const int n = swz * 4 + wid;
    const int b = n >> 9, qi = n & 511;

    int t = (qi == TQ - 1) ? (TT - 1)
          : (int)((double)qi * ((double)(TT - 1) / (double)(TQ - 1)));
    int j0 = t - (WW - 1); if (j0 < 0) j0 = 0;
    int j1 = t + (WW - 1); if (j1 > TT - 1) j1 = TT - 1;
    const int ncand = j1 - j0 + 1;                 // 12..23

    const int c = lane >> 2, i = lane & 3;
    const float* qrow = x + ((size_t)b * TT + t) * DD + i * 4;

    __shared__ double sc[4][24];

#pragma unroll
    for (int r = 0; r < 2; ++r) {
        int cc = r * 16 + c;
        double s0 = 0.0, s1 = 0.0;
        if (cc < ncand) {
            const float* krow = x + ((size_t)b * TT + (j0 + cc)) * DD + i * 4;
#pragma unroll 8
            for (int kk = 0; kk < 32; ++kk) {
                float4 qv = *(const float4*)(qrow + kk * 16);
                float4 kv = *(const float4*)(krow + kk * 16);
                s0 = fma((double)qv.x, (double)kv.x, s0);
                s1 = fma((double)qv.y, (double)kv.y, s1);
                s0 = fma((double)qv.z, (double)kv.z, s0);
                s1 = fma((double)qv.w, (double)kv.w, s1);
            }
        }
        double s = s0 + s1;
        s += __shfl_xor(s, 1);
        s += __shfl_xor(s, 2);
        if (i == 0 && cc < ncand) sc[wid][cc] = s;
    }
    __syncthreads();

    if (lane == 0) {
        int sel[WW]; unsigned used = 0;
        for (int k = 0; k < WW; ++k) {
            int best = -1; double bs = 0.0;
            for (int cc = 0; cc < ncand; ++cc) {
                if (used & (1u << cc)) continue;
                if (best < 0 || sc[wid][cc] > bs) { bs = sc[wid][cc]; best = cc; }
            }
            used |= (1u << best);
            sel[k] = j0 + best;
        }
        for (int a = 1; a < WW; ++a) {
            int v = sel[a]; int j = a - 1;
            while (j >= 0 && sel[j] > v) { sel[j + 1] = sel[j]; --j; }
            sel[j + 1] = v;
        }
#pragma unroll
        for (int k = 0; k < WW; ++k) ids[(size_t)n * WW + k] = sel[k];
    }
}

// -------- Kernel 2: f32 -> f16 weight conversion ---------------------------
__global__ __launch_bounds__(256) void convert_w_kernel(
    const float* __restrict__ wi, const float* __restrict__ wh, f16* __restrict__ w16)
{
    const int PER = 3 * DD * DD / 4;
    int i = blockIdx.x * 256 + threadIdx.x;
    float4 v;
    if (i < PER) v = ((const float4*)wi)[i];
    else         v = ((const float4*)wh)[i - PER];
    f16x4 o;
    o[0] = (_Float16)v.x; o[1] = (_Float16)v.y; o[2] = (_Float16)v.z; o[3] = (_Float16)v.w;
    *(f16x4*)(w16 + (size_t)i * 4) = o;
}

// -------- Kernel 3: one fused GRU step, f16 MFMA, double-buffered LDS ------
// Block: 256 thr / 4 waves; tile 128 rows x 64 cols; wave 64x32 (4 mf x 2 nf).
// K_STEP = 32, two 24KB LDS buffers; stage(k+1) issued before compute(k).
// LDS buffer layout: [gate 6][col 64][k 32] f16 (col row = 64 B, unswizzled —
// bank mapping is naturally balanced: 8 lanes per 4-bank group).
template<bool HAS_H>
__global__ __launch_bounds__(256, 2) void gru_step_kernel(
    const float* __restrict__ x,
    const int* __restrict__ ids,
    const f16* __restrict__ w16,        // [3072][512]
    const float* __restrict__ b_ih,
    const float* __restrict__ b_hh,
    const f16* __restrict__ h16r,       // null when !HAS_H
    f16* __restrict__ h16w,             // null on last step
    float* __restrict__ f32w,           // null except last step
    int step)
{
    __shared__ __align__(16) char sW[2][24 * 1024];
    __shared__ int sXrow[128];

    const int tid = threadIdx.x;
    const int lane = tid & 63, wid = tid >> 6;
    const int wm = wid >> 1, wn = wid & 1;
    const int l15 = lane & 15, lhi = lane >> 4;
    const int bid = blockIdx.x;
    const int rb = bid & 63, cb = bid >> 6;        // same rb -> same XCD
    const int row0 = rb * 128, c0 = cb * 64;

    if (tid < 128) {
        int nn = row0 + tid;
        int bb = nn >> 9;
        sXrow[tid] = bb * TT + ids[(size_t)nn * WW + step];
    }

    // staging: 6 chunks of 1KB per wave per buffer-fill (24 chunks total)
    // chunk ch = wid*6+ii: gate g = ch>>2, col group cg = ch&3 (16 cols)
    // lane: col_local = lane>>2, slot = lane&3 (slot = k-chunk of 8 elems)
    unsigned stOff[6];
    {
        const int slot = lane & 3, lc = lane >> 2;
#pragma unroll
        for (int ii = 0; ii < 6; ++ii) {
            int ch = wid * 6 + ii;
            int g = ch >> 2, cg = ch & 3;
            int col = cg * 16 + lc;
            unsigned grow = (unsigned)(g * 512 + c0 + col);
            stOff[ii] = grow * 1024u + (unsigned)(slot * 16);
        }
    }

    // stage ks=0 into buffer 0 (for !HAS_H skip hidden-weight gates 3..5)
#pragma unroll
    for (int ii = 0; ii < 6; ++ii) {
        if (HAS_H || (wid * 6 + ii) < 12) {
            const char* src = (const char*)w16 + stOff[ii];
            __builtin_amdgcn_global_load_lds(
                (const __attribute__((address_space(1))) unsigned*)src,
                (__attribute__((address_space(3))) unsigned*)(&sW[0][0] + (wid * 6 + ii) * 1024),
                16, 0, 0);
        }
    }

    __syncthreads();   // sXrow visible

    const float* xp[4]; const char* hp[4];
#pragma unroll
    for (int mf = 0; mf < 4; ++mf) {
        int rl = wm * 64 + mf * 16 + l15;
        xp[mf] = x + (size_t)sXrow[rl] * DD + lhi * 8;
        hp[mf] = (const char*)(h16r + (size_t)(row0 + rl) * DD + lhi * 8);
    }

    f32x4 accR[4][2], accZ[4][2], accIN[4][2], accHN[4][2];
#pragma unroll
    for (int mf = 0; mf < 4; ++mf)
#pragma unroll
        for (int nf = 0; nf < 2; ++nf) {
            f32x4 z = {0.f, 0.f, 0.f, 0.f};
            accR[mf][nf] = z; accZ[mf][nf] = z; accIN[mf][nf] = z; accHN[mf][nf] = z;
        }

    const int bcol = (wn * 32 + l15) * 64 + lhi * 16;   // B read base within buffer

    int cur = 0;
    for (int ks = 0; ks < 16; ++ks) {
        asm volatile("s_waitcnt vmcnt(0)" ::: "memory");
        __syncthreads();                          // buf[cur] staged; buf[cur^1] reads done

        if (ks < 15) {
            unsigned kadd = (unsigned)((ks + 1) * 64);   // 32 elems * 2 B
#pragma unroll
            for (int ii = 0; ii < 6; ++ii) {
                if (HAS_H || (wid * 6 + ii) < 12) {
                    const char* src = (const char*)w16 + stOff[ii] + kadd;
                    __builtin_amdgcn_global_load_lds(
                        (const __attribute__((address_space(1))) unsigned*)src,
                        (__attribute__((address_space(3))) unsigned*)(&sW[cur ^ 1][0] + (wid * 6 + ii) * 1024),
                        16, 0, 0);
                }
            }
        }

        const int k0 = ks * 32;

        // A operands (global, L2-hot)
        f16x8 ax[4], ah[4];
#pragma unroll
        for (int mf = 0; mf < 4; ++mf) {
            float4 xa = *(const float4*)(xp[mf] + k0);
            float4 xb = *(const float4*)(xp[mf] + k0 + 4);
            ax[mf] = cvt8(xa, xb);
            if (HAS_H) {
                uint4 hv = *(const uint4*)(hp[mf] + k0 * 2);
                ah[mf] = *(const f16x8*)&hv;
            }
        }

        // B fragments (LDS)
        const char* base = &sW[cur][0] + bcol;
        f16x8 Bv[2][6];
#pragma unroll
        for (int nf = 0; nf < 2; ++nf)
#pragma unroll
            for (int g = 0; g < 6; ++g)
                if (HAS_H || g < 3)
                    Bv[nf][g] = *(const f16x8*)(base + nf * 1024 + g * 4096);

#pragma unroll
        for (int nf = 0; nf < 2; ++nf)
#pragma unroll
            for (int mf = 0; mf < 4; ++mf) {
                accR[mf][nf]  = MFMA16(ax[mf], Bv[nf][0], accR[mf][nf]);
                accZ[mf][nf]  = MFMA16(ax[mf], Bv[nf][1], accZ[mf][nf]);
                accIN[mf][nf] = MFMA16(ax[mf], Bv[nf][2], accIN[mf][nf]);
                if (HAS_H) {
                    accR[mf][nf]  = MFMA16(ah[mf], Bv[nf][3], accR[mf][nf]);
                    accZ[mf][nf]  = MFMA16(ah[mf], Bv[nf][4], accZ[mf][nf]);
                    accHN[mf][nf] = MFMA16(ah[mf], Bv[nf][5], accHN[mf][nf]);
                }
            }
        cur ^= 1;
    }

    // epilogue
#pragma unroll
    for (int nf = 0; nf < 2; ++nf) {
        int col = c0 + wn * 32 + nf * 16 + l15;
        float bir = b_ih[col],          bhr = b_hh[col];
        float biz = b_ih[DD + col],     bhz = b_hh[DD + col];
        float bin = b_ih[2 * DD + col], bhn = b_hh[2 * DD + col];
#pragma unroll
        for (int mf = 0; mf < 4; ++mf) {
#pragma unroll
            for (int r = 0; r < 4; ++r) {
                int row = row0 + wm * 64 + mf * 16 + lhi * 4 + r;
                size_t off = (size_t)row * DD + col;
                float hold = HAS_H ? (float)h16r[off] : 0.0f;
                float R = fsigm(accR[mf][nf][r] + bir + bhr);
                float Z = fsigm(accZ[mf][nf][r] + biz + bhz);
                float Nn = ftanh(accIN[mf][nf][r] + bin + R * (accHN[mf][nf][r] + bhn));
                float res = (1.0f - Z) * Nn + Z * hold;
                if (h16w) h16w[off] = (f16)res;
                if (f32w) f32w[off] = res;
            }
        }
    }
}

// ---------------------------------------------------------------------------
extern "C" void kernel_launch(void* const* d_in, const int* in_sizes, int n_in,
                              void* d_out, int out_size, void* d_ws, size_t ws_size,
                              hipStream_t stream)
{
    const float* x    = (const float*)d_in[0];
    const float* w_ih = (const float*)d_in[1];
    const float* w_hh = (const float*)d_in[2];
    const float* b_ih = (const float*)d_in[3];
    const float* b_hh = (const float*)d_in[4];

    char* ws = (char*)d_ws;
    int*  ids = (int*)(ws + WS_IDS);
    f16*  w16 = (f16*)(ws + WS_W16);
    f16*  P0  = (f16*)(ws + WS_H16);       // ping
    f16*  P1  = (f16*)d_out;               // pong (aliases d_out; final step writes f32)

    select_topk_kernel<<<dim3(NROWS / 4), dim3(256), 0, stream>>>(x, ids);
    convert_w_kernel<<<dim3(1536), dim3(256), 0, stream>>>(w_ih, w_hh, w16);

    for (int s = 0; s < WW; ++s) {
        const f16* hr = (s == 0) ? nullptr : ((s & 1) ? P0 : P1);  // reads P[(s+1)&1]
        f16* hw      = (s == WW - 1) ? nullptr : ((s & 1) ? P1 : P0);  // writes P[s&1]
        float* fo    = (s == WW - 1) ? (float*)d_out : nullptr;
        if (s == 0)
            gru_step_kernel<false><<<dim3(512), dim3(256), 0, stream>>>(
                x, ids, w16, b_ih, b_hh, hr, hw, fo, s);
        else
            gru_step_kernel<true><<<dim3(512), dim3(256), 0, stream>>>(
                x, ids, w16, b_ih, b_hh, hr, hw, fo, s);
    }
}

// Round 4
// 522.890 us; speedup vs baseline: 8.6060x; 1.6849x over previous
//
#include <hip/hip_runtime.h>
#include <math.h>

// Problem constants
#define BB 16
#define TT 2048
#define DD 512
#define WW 12
#define TQ 512
#define NROWS (BB * TQ)

typedef _Float16 f16;
typedef __attribute__((ext_vector_type(8))) _Float16 f16x8;
typedef __attribute__((ext_vector_type(4))) _Float16 f16x4;
typedef __attribute__((ext_vector_type(4))) float f32x4;

#define MFMA16(a, b, c) __builtin_amdgcn_mfma_f32_16x16x32_f16((a), (b), (c), 0, 0, 0)

// ws layout
#define WS_IDS  0u
#define WS_W16  (512u * 1024u)              // 3072 x 512 f16 = 3 MB ([w_ih ; w_hh])
#define WS_H16  (4u * 1024u * 1024u)        // 8192 x 512 f16 = 8 MB (ping)

__device__ __forceinline__ float fsigm(float v) { return 1.0f / (1.0f + __expf(-v)); }
__device__ __forceinline__ float ftanh(float v) {
    float a = fabsf(v);
    float t = __expf(-2.0f * a);
    float r = (1.0f - t) / (1.0f + t);
    return copysignf(r, v);
}

__device__ __forceinline__ f16x8 cvt8(float4 a, float4 b) {
    f16x8 r;
    r[0] = (_Float16)a.x; r[1] = (_Float16)a.y; r[2] = (_Float16)a.z; r[3] = (_Float16)a.w;
    r[4] = (_Float16)b.x; r[5] = (_Float16)b.y; r[6] = (_Float16)b.z; r[7] = (_Float16)b.w;
    return r;
}

// -------- Kernel 1: band top-k selection, parallel rank-based ---------------
// 256 thr = 4 waves = 4 queries. Scores fp64 (exact vs fp32 ref ranking).
// Selection: lane j holds candidate j's score; rank via 23 shfl broadcasts;
// ballot+popcount emits sorted top-12. No LDS, no serial section.
__global__ __launch_bounds__(256) void select_topk_kernel(
    const float* __restrict__ x, int* __restrict__ ids)
{
    const int tid = threadIdx.x, wid = tid >> 6, lane = tid & 63;
    const int bid = blockIdx.x;                    // 0..2047
    const int swz = (bid & 7) * 256 + (bid >> 3);  // XCD-chunked
    const int n = swz * 4 + wid;
    const int b = n >> 9, qi = n & 511;

    int t = (qi == TQ - 1) ? (TT - 1)
          : (int)((double)qi * ((double)(TT - 1) / (double)(TQ - 1)));
    int j0 = t - (WW - 1); if (j0 < 0) j0 = 0;
    int j1 = t + (WW - 1); if (j1 > TT - 1) j1 = TT - 1;
    const int ncand = j1 - j0 + 1;                 // 12..23

    const int c = lane >> 2, i = lane & 3;
    const float* qrow = x + ((size_t)b * TT + t) * DD + i * 4;

    double sA = 0.0, sB2 = 0.0;
#pragma unroll
    for (int r = 0; r < 2; ++r) {
        int cc = r * 16 + c;
        double s0 = 0.0, s1 = 0.0;
        if (cc < ncand) {
            const float* krow = x + ((size_t)b * TT + (j0 + cc)) * DD + i * 4;
#pragma unroll 8
            for (int kk = 0; kk < 32; ++kk) {
                float4 qv = *(const float4*)(qrow + kk * 16);
                float4 kv = *(const float4*)(krow + kk * 16);
                s0 = fma((double)qv.x, (double)kv.x, s0);
                s1 = fma((double)qv.y, (double)kv.y, s1);
                s0 = fma((double)qv.z, (double)kv.z, s0);
                s1 = fma((double)qv.w, (double)kv.w, s1);
            }
        }
        double s = s0 + s1;
        s += __shfl_xor(s, 1);
        s += __shfl_xor(s, 2);
        if (r == 0) sA = s; else sB2 = s;
    }

    // redistribute: lane j <- score of candidate j (computed by lane 4*(j%16))
    int src = (lane < 16) ? lane * 4 : (lane - 16) * 4;
    double v0 = __shfl(sA, src);
    double v1 = __shfl(sB2, src);
    double sj = (lane < 16) ? v0 : v1;
    bool valid = lane < ncand;
    if (!valid) sj = -1.0e300;

    int rank = 0;
    for (int kk = 0; kk < 2 * WW - 1; ++kk) {
        if (kk >= ncand) break;                    // wave-uniform
        double bs = __shfl(sj, kk);
        rank += (bs > sj || (bs == sj && kk < lane)) ? 1 : 0;
    }
    bool sel = valid && (rank < WW);
    unsigned long long m = __ballot(sel);
    if (sel) {
        int pos = __popcll(m & ((1ull << lane) - 1ull));
        ids[(size_t)n * WW + pos] = j0 + lane;
    }
}

// -------- Kernel 2: f32 -> f16 weight conversion ---------------------------
__global__ __launch_bounds__(256) void convert_w_kernel(
    const float* __restrict__ wi, const float* __restrict__ wh, f16* __restrict__ w16)
{
    const int PER = 3 * DD * DD / 4;
    int i = blockIdx.x * 256 + threadIdx.x;
    float4 v;
    if (i < PER) v = ((const float4*)wi)[i];
    else         v = ((const float4*)wh)[i - PER];
    f16x4 o;
    o[0] = (_Float16)v.x; o[1] = (_Float16)v.y; o[2] = (_Float16)v.z; o[3] = (_Float16)v.w;
    *(f16x4*)(w16 + (size_t)i * 4) = o;
}

// -------- Kernel 3: fused GRU step, f16 MFMA, A+B LDS-staged ---------------
// Grid 256 = 32 rb x 8 cb; XCD k gets rb {4k..4k+3} x all cb (bid mapping).
// Block 512 thr / 8 waves (wm 0..3, wn 0..1); wave tile 64 rows x 32 cols.
// LDS (113 KB): B 2x24KB [gate6][col64][slot4x16B], x 2x16KB [row256][slot4],
// h 2x16KB same; all slots XOR-swizzled: slot ^= (row_or_col>>1)&3 (2-way max).
// x: reg-staged (global f32 -> cvt -> ds_write); B,h: per-lane-src global_load_lds.
template<bool HAS_H>
__global__ __launch_bounds__(512, 2) void gru_step_kernel(
    const float* __restrict__ x,
    const int* __restrict__ ids,
    const f16* __restrict__ w16,        // [3072][512]
    const float* __restrict__ b_ih,
    const float* __restrict__ b_hh,
    const f16* __restrict__ h16r,
    f16* __restrict__ h16w,
    float* __restrict__ f32w,
    int step)
{
    __shared__ __align__(16) char sB[2][24 * 1024];
    __shared__ __align__(16) char sX[2][16 * 1024];
    __shared__ __align__(16) char sH[2][16 * 1024];
    __shared__ int sXrow[256];

    const int tid = threadIdx.x;
    const int lane = tid & 63, wid = tid >> 6;
    const int wm = wid >> 1, wn = wid & 1;
    const int l15 = lane & 15, lhi = lane >> 4;
    const int bid = blockIdx.x;
    const int rb = (bid & 7) * 4 + (bid >> 6);     // XCD = bid%8 owns 4 rbs
    const int cb = (bid >> 3) & 7;
    const int row0 = rb * 256, c0 = cb * 64;

    if (tid < 256) {
        int nn = row0 + tid;
        sXrow[tid] = (nn >> 9) * TT + ids[(size_t)nn * WW + step];
    }
    __syncthreads();

    // ---- B staging: 3 chunks/wave (24 total; chunk = 1KB = 16 cols x 4 slots)
    const f16* bsrc[3]; int bdst[3]; bool bact[3];
    {
        const int slot = lane & 3, lc = lane >> 2;
#pragma unroll
        for (int ii = 0; ii < 3; ++ii) {
            int ch = wid * 3 + ii;
            int g = ch >> 2, cg = ch & 3;
            int col = cg * 16 + lc;
            bact[ii] = HAS_H || (g < 3);
            bsrc[ii] = w16 + ((size_t)(g * 512 + c0 + col) * 512
                              + (size_t)((slot ^ ((col >> 1) & 3)) * 8));
            bdst[ii] = ch * 1024;
        }
    }
    // ---- h staging: 2 chunks/wave (16 total; chunk = 16 rows x 4 slots)
    const f16* hsrc[2]; int hdst[2];
    if (HAS_H) {
        const int slot = lane & 3;
#pragma unroll
        for (int ii = 0; ii < 2; ++ii) {
            int ch = wid * 2 + ii;
            int row = ch * 16 + (lane >> 2);
            hsrc[ii] = h16r + ((size_t)(row0 + row) * 512
                               + (size_t)((slot ^ ((lane >> 3) & 3)) * 8));
            hdst[ii] = ch * 1024;
        }
    }
    // ---- x staging (reg path): 2 lanes/row; lane covers slots {2b, 2b+1}
    const int myrow = wid * 32 + (lane >> 1);
    const int bsel = lane & 1;
    const int cA = (2 * bsel) ^ ((myrow >> 1) & 3);   // source chunk for slot 2b
    const float* xsrc = x + (size_t)sXrow[myrow] * DD;
    const float* xp0 = xsrc + cA * 8;
    const float* xp1 = xsrc + (cA ^ 1) * 8;
    const int xw0 = myrow * 64 + (2 * bsel) * 16;     // LDS byte offset

    // ---- fragment read offsets (shared swizzle term)
    const int swzo = (lhi ^ ((l15 >> 1) & 3)) * 16;
    const int aA0 = (wm * 64 + l15) * 64 + swzo;      // + mf*1024
    int colb[2];
#pragma unroll
    for (int nf = 0; nf < 2; ++nf)
        colb[nf] = (wn * 32 + nf * 16 + l15) * 64 + swzo;   // + g*4096

    f32x4 accR[4][2], accZ[4][2], accIN[4][2], accHN[4][2];
#pragma unroll
    for (int mf = 0; mf < 4; ++mf)
#pragma unroll
        for (int nf = 0; nf < 2; ++nf) {
            f32x4 z = {0.f, 0.f, 0.f, 0.f};
            accR[mf][nf] = z; accZ[mf][nf] = z; accIN[mf][nf] = z; accHN[mf][nf] = z;
        }

    // ---- prologue: fill buffer 0 (k0 = 0)
    {
        float4 a0 = *(const float4*)(xp0);
        float4 a1 = *(const float4*)(xp0 + 4);
        float4 a2 = *(const float4*)(xp1);
        float4 a3 = *(const float4*)(xp1 + 4);
#pragma unroll
        for (int ii = 0; ii < 3; ++ii)
            if (bact[ii])
                __builtin_amdgcn_global_load_lds(
                    (const __attribute__((address_space(1))) unsigned*)bsrc[ii],
                    (__attribute__((address_space(3))) unsigned*)(&sB[0][0] + bdst[ii]), 16, 0, 0);
        if (HAS_H) {
#pragma unroll
            for (int ii = 0; ii < 2; ++ii)
                __builtin_amdgcn_global_load_lds(
                    (const __attribute__((address_space(1))) unsigned*)hsrc[ii],
                    (__attribute__((address_space(3))) unsigned*)(&sH[0][0] + hdst[ii]), 16, 0, 0);
        }
        *(f16x8*)(&sX[0][0] + xw0)      = cvt8(a0, a1);
        *(f16x8*)(&sX[0][0] + xw0 + 16) = cvt8(a2, a3);
    }

    int cur = 0;
    for (int ks = 0; ks < 16; ++ks) {
        asm volatile("s_waitcnt vmcnt(0)" ::: "memory");
        __syncthreads();                           // buf[cur] ready

        float4 a0, a1, a2, a3;
        const int kn = (ks + 1) * 32;
        if (ks < 15) {
            a0 = *(const float4*)(xp0 + kn);
            a1 = *(const float4*)(xp0 + kn + 4);
            a2 = *(const float4*)(xp1 + kn);
            a3 = *(const float4*)(xp1 + kn + 4);
#pragma unroll
            for (int ii = 0; ii < 3; ++ii)
                if (bact[ii])
                    __builtin_amdgcn_global_load_lds(
                        (const __attribute__((address_space(1))) unsigned*)(bsrc[ii] + kn),
                        (__attribute__((address_space(3))) unsigned*)(&sB[cur ^ 1][0] + bdst[ii]), 16, 0, 0);
            if (HAS_H) {
#pragma unroll
                for (int ii = 0; ii < 2; ++ii)
                    __builtin_amdgcn_global_load_lds(
                        (const __attribute__((address_space(1))) unsigned*)(hsrc[ii] + kn),
                        (__attribute__((address_space(3))) unsigned*)(&sH[cur ^ 1][0] + hdst[ii]), 16, 0, 0);
            }
        }

        // A fragments
        f16x8 ax[4], ah[4];
#pragma unroll
        for (int mf = 0; mf < 4; ++mf) {
            ax[mf] = *(const f16x8*)(&sX[cur][0] + aA0 + mf * 1024);
            if (HAS_H) ah[mf] = *(const f16x8*)(&sH[cur][0] + aA0 + mf * 1024);
        }

        // B fragments + MFMAs
#pragma unroll
        for (int nf = 0; nf < 2; ++nf) {
            const char* bb = &sB[cur][0] + colb[nf];
            f16x8 B0 = *(const f16x8*)(bb + 0 * 4096);
            f16x8 B1 = *(const f16x8*)(bb + 1 * 4096);
            f16x8 B2 = *(const f16x8*)(bb + 2 * 4096);
            f16x8 B3, B4, B5;
            if (HAS_H) {
                B3 = *(const f16x8*)(bb + 3 * 4096);
                B4 = *(const f16x8*)(bb + 4 * 4096);
                B5 = *(const f16x8*)(bb + 5 * 4096);
            }
#pragma unroll
            for (int mf = 0; mf < 4; ++mf) {
                accR[mf][nf]  = MFMA16(ax[mf], B0, accR[mf][nf]);
                accZ[mf][nf]  = MFMA16(ax[mf], B1, accZ[mf][nf]);
                accIN[mf][nf] = MFMA16(ax[mf], B2, accIN[mf][nf]);
                if (HAS_H) {
                    accR[mf][nf]  = MFMA16(ah[mf], B3, accR[mf][nf]);
                    accZ[mf][nf]  = MFMA16(ah[mf], B4, accZ[mf][nf]);
                    accHN[mf][nf] = MFMA16(ah[mf], B5, accHN[mf][nf]);
                }
            }
        }

        // late x-staging write (loads hidden under MFMAs)
        if (ks < 15) {
            *(f16x8*)(&sX[cur ^ 1][0] + xw0)      = cvt8(a0, a1);
            *(f16x8*)(&sX[cur ^ 1][0] + xw0 + 16) = cvt8(a2, a3);
        }
        cur ^= 1;
    }

    // ---- epilogue
#pragma unroll
    for (int nf = 0; nf < 2; ++nf) {
        int col = c0 + wn * 32 + nf * 16 + l15;
        float bir = b_ih[col],          bhr = b_hh[col];
        float biz = b_ih[DD + col],     bhz = b_hh[DD + col];
        float bin = b_ih[2 * DD + col], bhn = b_hh[2 * DD + col];
#pragma unroll
        for (int mf = 0; mf < 4; ++mf) {
#pragma unroll
            for (int r = 0; r < 4; ++r) {
                int row = row0 + wm * 64 + mf * 16 + lhi * 4 + r;
                size_t off = (size_t)row * DD + col;
                float hold = HAS_H ? (float)h16r[off] : 0.0f;
                float R = fsigm(accR[mf][nf][r] + bir + bhr);
                float Z = fsigm(accZ[mf][nf][r] + biz + bhz);
                float Nn = ftanh(accIN[mf][nf][r] + bin + R * (accHN[mf][nf][r] + bhn));
                float res = (1.0f - Z) * Nn + Z * hold;
                if (h16w) h16w[off] = (f16)res;
                if (f32w) f32w[off] = res;
            }
        }
    }
}

// ---------------------------------------------------------------------------
extern "C" void kernel_launch(void* const* d_in, const int* in_sizes, int n_in,
                              void* d_out, int out_size, void* d_ws, size_t ws_size,
                              hipStream_t stream)
{
    const float* x    = (const float*)d_in[0];
    const float* w_ih = (const float*)d_in[1];
    const float* w_hh = (const float*)d_in[2];
    const float* b_ih = (const float*)d_in[3];
    const float* b_hh = (const float*)d_in[4];

    char* ws = (char*)d_ws;
    int*  ids = (int*)(ws + WS_IDS);
    f16*  w16 = (f16*)(ws + WS_W16);
    f16*  P0  = (f16*)(ws + WS_H16);       // ping
    f16*  P1  = (f16*)d_out;               // pong (aliases d_out; last step writes f32)

    select_topk_kernel<<<dim3(NROWS / 4), dim3(256), 0, stream>>>(x, ids);
    convert_w_kernel<<<dim3(1536), dim3(256), 0, stream>>>(w_ih, w_hh, w16);

    for (int s = 0; s < WW; ++s) {
        const f16* hr = (s == 0) ? nullptr : ((s & 1) ? P0 : P1);
        f16* hw      = (s == WW - 1) ? nullptr : ((s & 1) ? P1 : P0);
        float* fo    = (s == WW - 1) ? (float*)d_out : nullptr;
        if (s == 0)
            gru_step_kernel<false><<<dim3(256), dim3(512), 0, stream>>>(
                x, ids, w16, b_ih, b_hh, hr, hw, fo, s);
        else
            gru_step_kernel<true><<<dim3(256), dim3(512), 0, stream>>>(
                x, ids, w16, b_ih, b_hh, hr, hw, fo, s);
    }
}